// Round 1
// baseline (75.872 us; speedup 1.0000x reference)
//
#include <hip/hip_runtime.h>

#define EPS_IOU 1e-6f

__global__ __launch_bounds__(256) void giou_partial_kernel(
    const float* __restrict__ pred, const float* __restrict__ target,
    float* __restrict__ partial, int n)
{
    int i = blockIdx.x * blockDim.x + threadIdx.x;
    float loss = 0.0f;
    if (i < n) {
        const float p0 = pred[5*i+0], p1 = pred[5*i+1], p2 = pred[5*i+2], p3 = pred[5*i+3], p4 = pred[5*i+4];
        const float t0 = target[5*i+0], t1 = target[5*i+1], t2 = target[5*i+2], t3 = target[5*i+3], t4 = target[5*i+4];

        // ---- box2corners ----
        float c1x[4], c1y[4], c2x[4], c2y[4];
        {
            const float DX[4] = {0.5f,-0.5f,-0.5f,0.5f};
            const float DY[4] = {0.5f, 0.5f,-0.5f,-0.5f};
            float cs = cosf(p4), sn = sinf(p4);
            #pragma unroll
            for (int k=0;k<4;k++){
                float dx = DX[k]*p2, dy = DY[k]*p3;
                c1x[k] = dx*cs - dy*sn + p0;
                c1y[k] = dx*sn + dy*cs + p1;
            }
            cs = cosf(t4); sn = sinf(t4);
            #pragma unroll
            for (int k=0;k<4;k++){
                float dx = DX[k]*t2, dy = DY[k]*t3;
                c2x[k] = dx*cs - dy*sn + t0;
                c2y[k] = dx*sn + dy*cs + t1;
            }
        }

        // ---- candidate vertices: 4 (c1) + 4 (c2) + 16 (edge intersections) ----
        float vx[32], vy[32], ang[32];
        bool  m[24];

        // corners_in_box(c1, c2) and (c2, c1)
        #pragma unroll
        for (int k=0;k<4;k++){
            // c1[k] in box2?
            {
                float ax=c2x[0], ay=c2y[0];
                float abx=c2x[1]-ax, aby=c2y[1]-ay;
                float adx=c2x[3]-ax, ady=c2y[3]-ay;
                float amx=c1x[k]-ax, amy=c1y[k]-ay;
                float rab = (abx*amx+aby*amy)/fmaxf(abx*abx+aby*aby, 1e-12f);
                float rad = (adx*amx+ady*amy)/fmaxf(adx*adx+ady*ady, 1e-12f);
                const float tol = 1e-6f;
                m[k] = (rab > -tol) && (rab < 1.f+tol) && (rad > -tol) && (rad < 1.f+tol);
                vx[k]=c1x[k]; vy[k]=c1y[k];
            }
            // c2[k] in box1?
            {
                float ax=c1x[0], ay=c1y[0];
                float abx=c1x[1]-ax, aby=c1y[1]-ay;
                float adx=c1x[3]-ax, ady=c1y[3]-ay;
                float amx=c2x[k]-ax, amy=c2y[k]-ay;
                float rab = (abx*amx+aby*amy)/fmaxf(abx*abx+aby*aby, 1e-12f);
                float rad = (adx*amx+ady*amy)/fmaxf(adx*adx+ady*ady, 1e-12f);
                const float tol = 1e-6f;
                m[4+k] = (rab > -tol) && (rab < 1.f+tol) && (rad > -tol) && (rad < 1.f+tol);
                vx[4+k]=c2x[k]; vy[4+k]=c2y[k];
            }
        }

        // edge-edge intersections, slot = 8 + e1*4 + e2
        #pragma unroll
        for (int e1=0;e1<4;e1++){
            float p1x=c1x[e1], p1y=c1y[e1];
            float d1x=c1x[(e1+1)&3]-p1x, d1y=c1y[(e1+1)&3]-p1y;
            #pragma unroll
            for (int e2=0;e2<4;e2++){
                float q1x=c2x[e2], q1y=c2y[e2];
                float d2x=c2x[(e2+1)&3]-q1x, d2y=c2y[(e2+1)&3]-q1y;
                float den = d1x*d2y - d1y*d2x;
                float dens = (fabsf(den) < 1e-12f) ? 1e-12f : den;
                float wx = q1x-p1x, wy = q1y-p1y;
                float t = (wx*d2y - wy*d2x)/dens;
                float u = (wx*d1y - wy*d1x)/dens;
                bool mm = (t>0.f)&&(t<1.f)&&(u>0.f)&&(u<1.f);
                int s = 8 + e1*4 + e2;
                float ix = p1x + t*d1x, iy = p1y + t*d1y;
                vx[s] = mm ? ix : 0.f;
                vy[s] = mm ? iy : 0.f;
                m[s]  = mm;
            }
        }

        // ---- centroid of masked verts, angles ----
        float sxs=0.f, sys=0.f, cnt=0.f;
        #pragma unroll
        for (int k=0;k<24;k++){ float mf = m[k]?1.f:0.f; sxs += vx[k]*mf; sys += vy[k]*mf; cnt += mf; }
        float inv = 1.f / fmaxf(cnt, 1.f);
        float cxx = sxs*inv, cyy = sys*inv;
        #pragma unroll
        for (int k=0;k<24;k++){
            ang[k] = m[k] ? atan2f(vy[k]-cyy, vx[k]-cxx) : 1.0e6f;
        }
        #pragma unroll
        for (int k=24;k<32;k++){ ang[k]=2.0e6f; vx[k]=0.f; vy[k]=0.f; }

        // ---- bitonic sort of 32 (ang ascending, payload vx,vy) — all constant indices ----
        #pragma unroll
        for (int k=2;k<=32;k<<=1){
            #pragma unroll
            for (int j=k>>1;j>0;j>>=1){
                #pragma unroll
                for (int ii=0;ii<32;ii++){
                    const int ll = ii ^ j;
                    if (ll > ii) {
                        const bool up = ((ii & k) == 0);
                        bool sw = up ? (ang[ii] > ang[ll]) : (ang[ii] < ang[ll]);
                        float ta=ang[ii], tx_=vx[ii], ty_=vy[ii];
                        ang[ii]= sw?ang[ll]:ang[ii]; vx[ii]= sw?vx[ll]:vx[ii]; vy[ii]= sw?vy[ll]:vy[ii];
                        ang[ll]= sw?ta:ang[ll];      vx[ll]= sw?tx_:vx[ll];    vy[ll]= sw?ty_:vy[ll];
                    }
                }
            }
        }

        // ---- replace invalid (ang>100) with sorted-first vertex ----
        float v0x = vx[0], v0y = vy[0];
        #pragma unroll
        for (int k=0;k<32;k++){
            bool bad = ang[k] > 100.f;
            vx[k] = bad ? v0x : vx[k];
            vy[k] = bad ? v0y : vy[k];
        }

        // ---- shoelace over the 32-cycle ----
        float acc = 0.f;
        #pragma unroll
        for (int k=0;k<32;k++){
            int kn = (k+1)&31;
            acc += vx[k]*vy[kn] - vy[k]*vx[kn];
        }
        float inter_area = 0.5f * fabsf(acc);

        // ---- union / iou ----
        float unionv = p2*p3 + t2*t3 - inter_area;
        float iou = fmaxf(inter_area/unionv, EPS_IOU);

        // ---- smallest enclosing rotated rect over the 8 edge directions ----
        float best = 3.4e38f, bw=0.f, bh=0.f;
        #pragma unroll
        for (int d=0; d<8; d++){
            float ex, ey;
            if (d<4){ ex = c1x[(d+1)&3]-c1x[d]; ey = c1y[(d+1)&3]-c1y[d]; }
            else    { int dd=d-4; ex = c2x[(dd+1)&3]-c2x[dd]; ey = c2y[(dd+1)&3]-c2y[dd]; }
            float nrm = sqrtf(ex*ex+ey*ey);
            float innv = 1.f / fmaxf(nrm, 1e-12f);
            float ux = ex*innv, uy = ey*innv;
            float mxpx=-3.4e38f, mnpx=3.4e38f, mxpy=-3.4e38f, mnpy=3.4e38f;
            #pragma unroll
            for (int q=0;q<8;q++){
                float qx = (q<4)?c1x[q]:c2x[q-4];
                float qy = (q<4)?c1y[q]:c2y[q-4];
                float pxv =  qx*ux + qy*uy;
                float pyv = -qx*uy + qy*ux;
                mxpx=fmaxf(mxpx,pxv); mnpx=fminf(mnpx,pxv);
                mxpy=fmaxf(mxpy,pyv); mnpy=fminf(mnpy,pyv);
            }
            float wd = mxpx-mnpx, hd = mxpy-mnpy;
            float ar = wd*hd;
            if (ar < best){ best=ar; bw=wd; bh=hd; }   // strict < == argmin first occurrence
        }

        float area_c = bw*bh;
        float r = (area_c - unionv)/area_c;
        float giou = iou*iou*iou - r*r*r;
        loss = 1.0f - giou;
    }

    // ---- block reduction (deterministic) ----
    #pragma unroll
    for (int off=32; off; off>>=1) loss += __shfl_down(loss, off, 64);
    __shared__ float smem[4];
    int lane = threadIdx.x & 63, wid = threadIdx.x >> 6;
    if (lane==0) smem[wid] = loss;
    __syncthreads();
    if (threadIdx.x==0){
        partial[blockIdx.x] = smem[0]+smem[1]+smem[2]+smem[3];
    }
}

__global__ __launch_bounds__(256) void reduce_final_kernel(
    const float* __restrict__ partial, int nb, float* __restrict__ out, float invn)
{
    float s = 0.f;
    for (int i=threadIdx.x; i<nb; i+=256) s += partial[i];
    #pragma unroll
    for (int off=32; off; off>>=1) s += __shfl_down(s, off, 64);
    __shared__ float smem[4];
    int lane = threadIdx.x & 63, wid = threadIdx.x >> 6;
    if (lane==0) smem[wid] = s;
    __syncthreads();
    if (threadIdx.x==0){
        out[0] = (smem[0]+smem[1]+smem[2]+smem[3]) * invn;
    }
}

extern "C" void kernel_launch(void* const* d_in, const int* in_sizes, int n_in,
                              void* d_out, int out_size, void* d_ws, size_t ws_size,
                              hipStream_t stream) {
    const float* pred   = (const float*)d_in[0];
    const float* target = (const float*)d_in[1];
    float* out = (float*)d_out;
    float* partial = (float*)d_ws;
    int n  = in_sizes[0] / 5;
    int nb = (n + 255) / 256;
    giou_partial_kernel<<<nb, 256, 0, stream>>>(pred, target, partial, n);
    reduce_final_kernel<<<1, 256, 0, stream>>>(partial, nb, out, 1.0f/(float)n);
}

// Round 2
// 23.492 us; speedup vs baseline: 3.2298x; 3.2298x over previous
//
#include <hip/hip_runtime.h>

// Order-free intersection area of two convex CCW quads via Green's theorem:
// for each edge of P, clip to Q's 4 half-planes (single interval), contribution
// cross(seg_start, seg_end); plus same with P/Q swapped. Sum = 2*Area.
__device__ __forceinline__ float clip_sum(const float* px, const float* py,
                                          const float* qx, const float* qy)
{
    float acc = 0.f;
    #pragma unroll
    for (int e = 0; e < 4; e++) {
        float axv = px[e], ayv = py[e];
        float bxv = px[(e+1)&3], byv = py[(e+1)&3];
        float t0 = 0.f, t1 = 1.f;
        bool empty = false;
        #pragma unroll
        for (int k = 0; k < 4; k++) {
            float qxk = qx[k], qyk = qy[k];
            float ex = qx[(k+1)&3] - qxk, ey = qy[(k+1)&3] - qyk;
            // signed distance (scaled): >=0 means inside (left of CCW edge)
            float sa = ex*(ayv - qyk) - ey*(axv - qxk);
            float sb = ex*(byv - qyk) - ey*(bxv - qxk);
            bool ain = sa >= 0.f, bin = sb >= 0.f;
            float ts = sa / (sa - sb);   // only consumed when signs differ (den != 0)
            t1 = (ain && !bin) ? fminf(t1, ts) : t1;
            t0 = (!ain && bin) ? fmaxf(t0, ts) : t0;
            empty = empty || (!ain && !bin);
        }
        bool valid = (!empty) && (t1 > t0);
        float dx = bxv - axv, dy = byv - ayv;
        float pax = axv + t0*dx, pay = ayv + t0*dy;
        float pbx = axv + t1*dx, pby = ayv + t1*dy;
        float c = pax*pby - pay*pbx;
        acc += valid ? c : 0.f;
    }
    return acc;
}

// width/height of bounding rect of the 8 corners in rotated frame (ux,uy)
__device__ __forceinline__ void rect_wh(float ux, float uy,
                                        const float* ax, const float* ay,
                                        const float* bx, const float* by,
                                        float& w, float& h)
{
    float mxx = -3.4e38f, mnx = 3.4e38f, mxy = -3.4e38f, mny = 3.4e38f;
    #pragma unroll
    for (int q = 0; q < 4; q++) {
        float px =  ax[q]*ux + ay[q]*uy;
        float py = -ax[q]*uy + ay[q]*ux;
        mxx = fmaxf(mxx, px); mnx = fminf(mnx, px);
        mxy = fmaxf(mxy, py); mny = fminf(mny, py);
        px =  bx[q]*ux + by[q]*uy;
        py = -bx[q]*uy + by[q]*ux;
        mxx = fmaxf(mxx, px); mnx = fminf(mnx, px);
        mxy = fmaxf(mxy, py); mny = fminf(mny, py);
    }
    w = mxx - mnx; h = mxy - mny;
}

__global__ __launch_bounds__(256) void giou_partial_kernel(
    const float* __restrict__ pred, const float* __restrict__ target,
    float* __restrict__ partial, int n)
{
    int i = blockIdx.x * blockDim.x + threadIdx.x;
    float loss = 0.0f;
    if (i < n) {
        const float p0 = pred[5*i+0], p1 = pred[5*i+1], p2 = pred[5*i+2], p3 = pred[5*i+3], p4 = pred[5*i+4];
        const float q0 = target[5*i+0], q1 = target[5*i+1], q2 = target[5*i+2], q3 = target[5*i+3], q4 = target[5*i+4];

        // common center for f32 cancellation (exact for closed-loop area & max-min widths)
        float cx = 0.5f*(p0 + q0), cy = 0.5f*(p1 + q1);

        // ---- corners (centered), CCW ----
        float ax[4], ay[4], bx[4], by[4];
        {
            const float DX[4] = {0.5f,-0.5f,-0.5f,0.5f};
            const float DY[4] = {0.5f, 0.5f,-0.5f,-0.5f};
            float cs = cosf(p4), sn = sinf(p4);
            float ox = p0 - cx, oy = p1 - cy;
            #pragma unroll
            for (int k = 0; k < 4; k++) {
                float dx = DX[k]*p2, dy = DY[k]*p3;
                ax[k] = dx*cs - dy*sn + ox;
                ay[k] = dx*sn + dy*cs + oy;
            }
            cs = cosf(q4); sn = sinf(q4);
            ox = q0 - cx; oy = q1 - cy;
            #pragma unroll
            for (int k = 0; k < 4; k++) {
                float dx = DX[k]*q2, dy = DY[k]*q3;
                bx[k] = dx*cs - dy*sn + ox;
                by[k] = dx*sn + dy*cs + oy;
            }
        }

        // ---- intersection area (order-free Green's sum) ----
        float twoA = clip_sum(ax, ay, bx, by) + clip_sum(bx, by, ax, ay);
        float inter_area = 0.5f * fabsf(twoA);

        // ---- union / iou ----
        float unionv = p2*p3 + q2*q3 - inter_area;
        float iou = fmaxf(inter_area / unionv, 1e-6f);

        // ---- smallest enclosing rotated rect: only 2 distinct directions ----
        float e0x = ax[1] - ax[0], e0y = ay[1] - ay[0];
        float inv1 = 1.f / fmaxf(sqrtf(e0x*e0x + e0y*e0y), 1e-12f);
        float w1, h1; rect_wh(e0x*inv1, e0y*inv1, ax, ay, bx, by, w1, h1);
        float a1 = w1*h1;

        float e1x = bx[1] - bx[0], e1y = by[1] - by[0];
        float inv2 = 1.f / fmaxf(sqrtf(e1x*e1x + e1y*e1y), 1e-12f);
        float w2, h2; rect_wh(e1x*inv2, e1y*inv2, ax, ay, bx, by, w2, h2);
        float a2 = w2*h2;

        float area_c = (a2 < a1) ? a2 : a1;   // box1 dirs come first in ref's argmin

        float r = (area_c - unionv) / area_c;
        float giou = iou*iou*iou - r*r*r;
        loss = 1.0f - giou;
    }

    // ---- deterministic block reduction ----
    #pragma unroll
    for (int off = 32; off; off >>= 1) loss += __shfl_down(loss, off, 64);
    __shared__ float smem[4];
    int lane = threadIdx.x & 63, wid = threadIdx.x >> 6;
    if (lane == 0) smem[wid] = loss;
    __syncthreads();
    if (threadIdx.x == 0) {
        partial[blockIdx.x] = smem[0] + smem[1] + smem[2] + smem[3];
    }
}

__global__ __launch_bounds__(256) void reduce_final_kernel(
    const float* __restrict__ partial, int nb, float* __restrict__ out, float invn)
{
    float s = 0.f;
    for (int i = threadIdx.x; i < nb; i += 256) s += partial[i];
    #pragma unroll
    for (int off = 32; off; off >>= 1) s += __shfl_down(s, off, 64);
    __shared__ float smem[4];
    int lane = threadIdx.x & 63, wid = threadIdx.x >> 6;
    if (lane == 0) smem[wid] = s;
    __syncthreads();
    if (threadIdx.x == 0) {
        out[0] = (smem[0] + smem[1] + smem[2] + smem[3]) * invn;
    }
}

extern "C" void kernel_launch(void* const* d_in, const int* in_sizes, int n_in,
                              void* d_out, int out_size, void* d_ws, size_t ws_size,
                              hipStream_t stream) {
    const float* pred   = (const float*)d_in[0];
    const float* target = (const float*)d_in[1];
    float* out = (float*)d_out;
    float* partial = (float*)d_ws;
    int n  = in_sizes[0] / 5;
    int nb = (n + 255) / 256;
    giou_partial_kernel<<<nb, 256, 0, stream>>>(pred, target, partial, n);
    reduce_final_kernel<<<1, 256, 0, stream>>>(partial, nb, out, 1.0f/(float)n);
}

// Round 3
// 20.157 us; speedup vs baseline: 3.7641x; 1.1655x over previous
//
#include <hip/hip_runtime.h>

__device__ __forceinline__ float frcp(float x){ return __builtin_amdgcn_rcpf(x); }

// Clip P's 4 edges against Q's 4 half-planes using a precomputed s-table
// (s[p][k] = scaled signed distance of P corner p to Q plane k, >=0 inside).
// Returns sum of cross(start,end) over kept sub-segments (order-free Green sum).
__device__ __forceinline__ float clip_half(const float px[4], const float py[4],
                                           const float s[4][4])
{
    float acc = 0.f;
    #pragma unroll
    for (int e = 0; e < 4; e++) {
        const int en = (e+1)&3;
        float t0 = 0.f, t1 = 1.f;
        bool empty = false;
        #pragma unroll
        for (int k = 0; k < 4; k++) {
            float sa = s[e][k], sb = s[en][k];
            bool ain = sa >= 0.f, bin = sb >= 0.f;
            float ts = sa * frcp(sa - sb);   // only consumed when signs differ
            t1 = (ain && !bin) ? fminf(t1, ts) : t1;
            t0 = (!ain && bin) ? fmaxf(t0, ts) : t0;
            empty = empty || (!ain && !bin);
        }
        bool valid = (!empty) && (t1 > t0);
        float axv = px[e], ayv = py[e];
        float dx = px[en] - axv, dy = py[en] - ayv;
        float pax = fmaf(t0, dx, axv), pay = fmaf(t0, dy, ayv);
        float pbx = fmaf(t1, dx, axv), pby = fmaf(t1, dy, ayv);
        acc += valid ? (pax*pby - pay*pbx) : 0.f;
    }
    return acc;
}

__global__ __launch_bounds__(256) void giou_partial_kernel(
    const float* __restrict__ pred, const float* __restrict__ target,
    float* __restrict__ partial, int n)
{
    int i = blockIdx.x * blockDim.x + threadIdx.x;
    float loss = 0.0f;
    if (i < n) {
        const float p0 = pred[5*i+0], p1 = pred[5*i+1], p2 = pred[5*i+2], p3 = pred[5*i+3], p4 = pred[5*i+4];
        const float q0 = target[5*i+0], q1 = target[5*i+1], q2 = target[5*i+2], q3 = target[5*i+3], q4 = target[5*i+4];

        // common center for f32 cancellation
        const float cx = 0.5f*(p0 + q0), cy = 0.5f*(p1 + q1);
        const float oax = p0 - cx, oay = p1 - cy;
        const float obx = q0 - cx, oby = q1 - cy;

        const float cs1 = __cosf(p4), sn1 = __sinf(p4);
        const float cs2 = __cosf(q4), sn2 = __sinf(q4);

        // ---- corners (centered), CCW ----
        float ax[4], ay[4], bx[4], by[4];
        {
            const float DX[4] = {0.5f,-0.5f,-0.5f,0.5f};
            const float DY[4] = {0.5f, 0.5f,-0.5f,-0.5f};
            #pragma unroll
            for (int k = 0; k < 4; k++) {
                float dx = DX[k]*p2, dy = DY[k]*p3;
                ax[k] = dx*cs1 - dy*sn1 + oax;
                ay[k] = dx*sn1 + dy*cs1 + oay;
            }
            #pragma unroll
            for (int k = 0; k < 4; k++) {
                float dx = DX[k]*q2, dy = DY[k]*q3;
                bx[k] = dx*cs2 - dy*sn2 + obx;
                by[k] = dx*sn2 + dy*cs2 + oby;
            }
        }

        // ---- intersection area: order-free Green sum, s-tables reused ----
        float twoA;
        {
            float s[4][4];
            // A corners vs B planes
            #pragma unroll
            for (int k = 0; k < 4; k++) {
                float ex = bx[(k+1)&3] - bx[k], ey = by[(k+1)&3] - by[k];
                float qxk = bx[k], qyk = by[k];
                #pragma unroll
                for (int p = 0; p < 4; p++)
                    s[p][k] = ex*(ay[p]-qyk) - ey*(ax[p]-qxk);
            }
            twoA = clip_half(ax, ay, s);
            // B corners vs A planes
            #pragma unroll
            for (int k = 0; k < 4; k++) {
                float ex = ax[(k+1)&3] - ax[k], ey = ay[(k+1)&3] - ay[k];
                float qxk = ax[k], qyk = ay[k];
                #pragma unroll
                for (int p = 0; p < 4; p++)
                    s[p][k] = ex*(by[p]-qyk) - ey*(bx[p]-qxk);
            }
            twoA += clip_half(bx, by, s);
        }
        float inter_area = 0.5f * fabsf(twoA);

        // ---- union / iou ----
        float unionv = p2*p3 + q2*q3 - inter_area;
        float iou = fmaxf(inter_area * frcp(unionv), 1e-6f);

        // ---- smallest enclosing rect, closed form over the 2 distinct dirs ----
        // support of a rect along unit u: center.u +- 0.5*(w*|cosD| + h*|sinD|)
        float cD = cs1*cs2 + sn1*sn2;
        float sD = sn2*cs1 - cs2*sn1;
        float acd = fabsf(cD), asd = fabsf(sD);

        // direction = box1 axes
        float pAu = oax*cs1 + oay*sn1, pAv = -oax*sn1 + oay*cs1;
        float pBu = obx*cs1 + oby*sn1, pBv = -obx*sn1 + oby*cs1;
        float eAx = 0.5f*p2, eAy = 0.5f*p3;
        float eBx = 0.5f*(q2*acd + q3*asd), eBy = 0.5f*(q2*asd + q3*acd);
        float w1 = fmaxf(pAu+eAx, pBu+eBx) - fminf(pAu-eAx, pBu-eBx);
        float h1 = fmaxf(pAv+eAy, pBv+eBy) - fminf(pAv-eAy, pBv-eBy);
        float a1 = w1*h1;

        // direction = box2 axes
        float pAu2 = oax*cs2 + oay*sn2, pAv2 = -oax*sn2 + oay*cs2;
        float pBu2 = obx*cs2 + oby*sn2, pBv2 = -obx*sn2 + oby*cs2;
        float eB2x = 0.5f*q2, eB2y = 0.5f*q3;
        float eA2x = 0.5f*(p2*acd + p3*asd), eA2y = 0.5f*(p2*asd + p3*acd);
        float w2 = fmaxf(pAu2+eA2x, pBu2+eB2x) - fminf(pAu2-eA2x, pBu2-eB2x);
        float h2 = fmaxf(pAv2+eA2y, pBv2+eB2y) - fminf(pAv2-eA2y, pBv2-eB2y);
        float a2 = w2*h2;

        float area_c = (a2 < a1) ? a2 : a1;   // box1 dirs first in ref argmin

        float r = (area_c - unionv) * frcp(area_c);
        float giou = iou*iou*iou - r*r*r;
        loss = 1.0f - giou;
    }

    // ---- deterministic block reduction ----
    #pragma unroll
    for (int off = 32; off; off >>= 1) loss += __shfl_down(loss, off, 64);
    __shared__ float smem[4];
    int lane = threadIdx.x & 63, wid = threadIdx.x >> 6;
    if (lane == 0) smem[wid] = loss;
    __syncthreads();
    if (threadIdx.x == 0) {
        partial[blockIdx.x] = smem[0] + smem[1] + smem[2] + smem[3];
    }
}

__global__ __launch_bounds__(256) void reduce_final_kernel(
    const float* __restrict__ partial, int nb, float* __restrict__ out, float invn)
{
    float s = 0.f;
    for (int i = threadIdx.x; i < nb; i += 256) s += partial[i];
    #pragma unroll
    for (int off = 32; off; off >>= 1) s += __shfl_down(s, off, 64);
    __shared__ float smem[4];
    int lane = threadIdx.x & 63, wid = threadIdx.x >> 6;
    if (lane == 0) smem[wid] = s;
    __syncthreads();
    if (threadIdx.x == 0) {
        out[0] = (smem[0] + smem[1] + smem[2] + smem[3]) * invn;
    }
}

extern "C" void kernel_launch(void* const* d_in, const int* in_sizes, int n_in,
                              void* d_out, int out_size, void* d_ws, size_t ws_size,
                              hipStream_t stream) {
    const float* pred   = (const float*)d_in[0];
    const float* target = (const float*)d_in[1];
    float* out = (float*)d_out;
    float* partial = (float*)d_ws;
    int n  = in_sizes[0] / 5;
    int nb = (n + 255) / 256;
    giou_partial_kernel<<<nb, 256, 0, stream>>>(pred, target, partial, n);
    reduce_final_kernel<<<1, 256, 0, stream>>>(partial, nb, out, 1.0f/(float)n);
}